// Round 7
// baseline (195.351 us; speedup 1.0000x reference)
//
#include <hip/hip_runtime.h>
#include <hip/hip_bf16.h>

#define N_NODES 50000
#define N_EDGES 800000
#define DIM     128
#define N_STRIPS (N_NODES / 16)               // 3125 exact: 16-row strips
#define N_BKT    ((N_NODES + 255) / 256)      // 196 buckets (dst >> 8)
#define EDGE_BLOCKS ((N_EDGES + 4095) / 4096) // 196 chunks of 4096 edges
#define BUF_CAP  6144                          // LDS edge buffer (mean 4096, 32 sigma)
#define GEMM_BLOCKS ((N_STRIPS + 3) / 4)      // 782
#define HIST_BLOCK0 GEMM_BLOCKS               // 782..978: hist chunks
#define PACK_BLOCK0 (GEMM_BLOCKS + EDGE_BLOCKS) // 978..994: weight pack
#define FRONT_BLOCKS (PACK_BLOCK0 + 16)       // 994
#define CHUNKS_PER_PART (EDGE_BLOCKS / 4)     // 49 exact

typedef short short8 __attribute__((ext_vector_type(8)));
typedef float floatx4 __attribute__((ext_vector_type(4)));

// fp32 -> bf16 (RNE) bit pattern
__device__ inline unsigned short f2bf(float f) {
    __hip_bfloat16 h = __float2bfloat16(f);
    return *reinterpret_cast<unsigned short*>(&h);
}

// ---------------------------------------------------------------------------
// Prologue: pack W into MFMA B-fragment order (p1), 8 blocks.
// slot s=(ks*8+nt)*64+lane holds 8 bf16: B[ks*32+(lane>>4)*8+j][nt*16+(lane&15)]
// ---------------------------------------------------------------------------
__global__ __launch_bounds__(256) void pack_w1(
    const float* __restrict__ W, uint4* __restrict__ p1)
{
    const int s    = blockIdx.x * 256 + threadIdx.x;     // 0..2047
    const int lane = s & 63;
    const int nt   = (s >> 6) & 7;
    const int ks   = s >> 9;
    const int m    = lane & 15;
    const int q    = lane >> 4;
    unsigned short e[8];
    #pragma unroll
    for (int j = 0; j < 8; ++j)
        e[j] = f2bf(W[(ks * 32 + q * 8 + j) * DIM + nt * 16 + m]);
    uint4 o;
    o.x = (unsigned)e[0] | ((unsigned)e[1] << 16);
    o.y = (unsigned)e[2] | ((unsigned)e[3] << 16);
    o.z = (unsigned)e[4] | ((unsigned)e[5] << 16);
    o.w = (unsigned)e[6] | ((unsigned)e[7] << 16);
    p1[s] = o;
}

// ---------------------------------------------------------------------------
// Fused front end. Block ranges:
//  [0, 782):   GEMM1 (MFMA, no LDS): support = bf16(x @ W + b), 4 waves/block
//  [782, 978): per-chunk bucket histogram (bucket = dst>>8) -> blk_hist
//  [978, 994): pack W2 (B[k][n]=W2[n][k]) -> p2 (consumed 4 dispatches later)
// ---------------------------------------------------------------------------
__global__ __launch_bounds__(256) void fused_front(
    const float* __restrict__ x, const float* __restrict__ W2,
    const float* __restrict__ bias, const int* __restrict__ dst,
    const uint4* __restrict__ p1,
    unsigned short* __restrict__ support, int* __restrict__ blk_hist,
    uint4* __restrict__ p2)
{
    __shared__ int bh[256];
    const int t = threadIdx.x;

    if (blockIdx.x < HIST_BLOCK0) {
        // ---------------- GEMM1 ----------------
        const int wave  = t >> 6;
        const int lane  = t & 63;
        const int strip = blockIdx.x * 4 + wave;
        if (strip >= N_STRIPS) return;
        const int m = lane & 15;
        const int q = lane >> 4;
        const int row = strip * 16 + m;

        short8 a[4];
        const float4* xr = reinterpret_cast<const float4*>(&x[(size_t)row * DIM]);
        #pragma unroll
        for (int ks = 0; ks < 4; ++ks) {
            const float4 f0 = xr[ks * 8 + q * 2];
            const float4 f1 = xr[ks * 8 + q * 2 + 1];
            short8 tt;
            tt[0] = (short)f2bf(f0.x); tt[1] = (short)f2bf(f0.y);
            tt[2] = (short)f2bf(f0.z); tt[3] = (short)f2bf(f0.w);
            tt[4] = (short)f2bf(f1.x); tt[5] = (short)f2bf(f1.y);
            tt[6] = (short)f2bf(f1.z); tt[7] = (short)f2bf(f1.w);
            a[ks] = tt;
        }

        floatx4 acc[8];
        #pragma unroll
        for (int nt = 0; nt < 8; ++nt) { acc[nt][0]=0.f; acc[nt][1]=0.f; acc[nt][2]=0.f; acc[nt][3]=0.f; }

        const short8* Bp = (const short8*)p1;
        #pragma unroll
        for (int ks = 0; ks < 4; ++ks) {
            #pragma unroll
            for (int nt = 0; nt < 8; ++nt) {
                const short8 bf = Bp[(ks * 8 + nt) * 64 + lane];
                acc[nt] = __builtin_amdgcn_mfma_f32_16x16x32_bf16(a[ks], bf, acc[nt], 0, 0, 0);
            }
        }

        #pragma unroll
        for (int nt = 0; nt < 8; ++nt) {
            const float bb = bias[nt * 16 + m];
            #pragma unroll
            for (int i = 0; i < 4; ++i) {
                const int r = strip * 16 + q * 4 + i;
                support[(size_t)r * DIM + nt * 16 + m] = f2bf(acc[nt][i] + bb);
            }
        }
    } else if (blockIdx.x < PACK_BLOCK0) {
        // ---------------- blockwise bucket histogram ----------------
        const int chunk = blockIdx.x - HIST_BLOCK0;
        bh[t] = 0;
        __syncthreads();
        const int base   = chunk * 4096;
        const int navail = min(4096, N_EDGES - base);    // 4096 or 1280; %4==0
        const int4* d4 = reinterpret_cast<const int4*>(dst + base);
        #pragma unroll
        for (int i = 0; i < 4; ++i) {
            const int j = t + i * 256;
            if (j * 4 < navail) {
                const int4 d = d4[j];
                atomicAdd(&bh[d.x >> 8], 1);
                atomicAdd(&bh[d.y >> 8], 1);
                atomicAdd(&bh[d.z >> 8], 1);
                atomicAdd(&bh[d.w >> 8], 1);
            }
        }
        __syncthreads();
        blk_hist[chunk * 256 + t] = bh[t];
    } else {
        // ---------------- pack W2 ----------------
        const int pb   = blockIdx.x - PACK_BLOCK0;       // 0..15, pairs cover 2048 slots
        const int s    = (pb & 7) * 256 + t;             // 0..2047
        if (pb >= 8) return;                             // 8 blocks suffice
        const int lane = s & 63;
        const int nt   = (s >> 6) & 7;
        const int ks   = s >> 9;
        const int m    = lane & 15;
        const int q    = lane >> 4;
        const float4 f0 = *reinterpret_cast<const float4*>(&W2[(nt * 16 + m) * DIM + ks * 32 + q * 8]);
        const float4 f1 = *reinterpret_cast<const float4*>(&W2[(nt * 16 + m) * DIM + ks * 32 + q * 8 + 4]);
        unsigned short e[8];
        e[0] = f2bf(f0.x); e[1] = f2bf(f0.y); e[2] = f2bf(f0.z); e[3] = f2bf(f0.w);
        e[4] = f2bf(f1.x); e[5] = f2bf(f1.y); e[6] = f2bf(f1.z); e[7] = f2bf(f1.w);
        uint4 o;
        o.x = (unsigned)e[0] | ((unsigned)e[1] << 16);
        o.y = (unsigned)e[2] | ((unsigned)e[3] << 16);
        o.z = (unsigned)e[4] | ((unsigned)e[5] << 16);
        o.w = (unsigned)e[6] | ((unsigned)e[7] << 16);
        p2[s] = o;
    }
}

// ---------------------------------------------------------------------------
// Scan per-chunk histograms -> per-chunk per-bucket scatter bases (blk_base)
// + bucket starts (bbase[197]). One block x 1024: 4 parts x 256 buckets.
// Per-chunk prefixes held in registers (49 unrolled) -> single global pass each way.
// ---------------------------------------------------------------------------
__global__ __launch_bounds__(1024) void scan_hist(
    const int* __restrict__ blk_hist, int* __restrict__ blk_base,
    int* __restrict__ bbase)
{
    __shared__ int psum[4][256];
    __shared__ int stot[256];
    __shared__ int sinc[256];

    const int t    = threadIdx.x;
    const int b    = t & 255;
    const int part = t >> 8;
    const int c0   = part * CHUNKS_PER_PART;

    int pre[CHUNKS_PER_PART];
    int run = 0;
    #pragma unroll
    for (int k = 0; k < CHUNKS_PER_PART; ++k) {
        const int v = blk_hist[(c0 + k) * 256 + b];
        pre[k] = run;
        run += v;
    }
    psum[part][b] = run;
    __syncthreads();

    if (part == 0) {
        const int tot = psum[0][b] + psum[1][b] + psum[2][b] + psum[3][b];
        stot[b] = tot;
        sinc[b] = tot;
    }
    __syncthreads();
    for (int off = 1; off < 256; off <<= 1) {
        int u = 0;
        if (part == 0 && b >= off) u = sinc[b - off];
        __syncthreads();
        if (part == 0 && b >= off) sinc[b] += u;
        __syncthreads();
    }
    const int ex = sinc[b] - stot[b];        // exclusive bucket base
    if (part == 0 && b < N_BKT) bbase[b] = ex;
    if (t == 0) bbase[N_BKT] = N_EDGES;

    int partbase = 0;
    #pragma unroll
    for (int p = 0; p < 4; ++p) if (p < part) partbase += psum[p][b];
    const int add = ex + partbase;
    #pragma unroll
    for (int k = 0; k < CHUNKS_PER_PART; ++k)
        blk_base[(c0 + k) * 256 + b] = pre[k] + add;
}

// ---------------------------------------------------------------------------
// Deterministic bucket scatter: bases precomputed per (chunk,bucket); only
// LDS atomics for within-chunk ordering. Writes land in contiguous runs.
// Payload: word0 = src | (dst&0xFF)<<16, word1 = val bits.
// ---------------------------------------------------------------------------
__global__ __launch_bounds__(256) void bucket_scatter(
    const int* __restrict__ src, const int* __restrict__ dst,
    const float* __restrict__ vals, const int* __restrict__ blk_base,
    int2* __restrict__ bucketed)
{
    __shared__ int rcur[256];
    const int t     = threadIdx.x;
    const int chunk = blockIdx.x;
    rcur[t] = blk_base[chunk * 256 + t];
    __syncthreads();

    const int base   = chunk * 4096;
    const int navail = min(4096, N_EDGES - base);
    const int4*   s4 = reinterpret_cast<const int4*>(src + base);
    const int4*   d4 = reinterpret_cast<const int4*>(dst + base);
    const float4* v4 = reinterpret_cast<const float4*>(vals + base);
    #pragma unroll
    for (int i = 0; i < 4; ++i) {
        const int j = t + i * 256;
        if (j * 4 < navail) {
            const int4   s = s4[j];
            const int4   d = d4[j];
            const float4 v = v4[j];
            int p;
            p = atomicAdd(&rcur[d.x >> 8], 1);
            bucketed[p] = make_int2((s.x & 0xFFFF) | ((d.x & 0xFF) << 16), __float_as_int(v.x));
            p = atomicAdd(&rcur[d.y >> 8], 1);
            bucketed[p] = make_int2((s.y & 0xFFFF) | ((d.y & 0xFF) << 16), __float_as_int(v.y));
            p = atomicAdd(&rcur[d.z >> 8], 1);
            bucketed[p] = make_int2((s.z & 0xFFFF) | ((d.z & 0xFF) << 16), __float_as_int(v.z));
            p = atomicAdd(&rcur[d.w >> 8], 1);
            bucketed[p] = make_int2((s.w & 0xFFFF) | ((d.w & 0xFF) << 16), __float_as_int(v.w));
        }
    }
}

// ---------------------------------------------------------------------------
// One block (512 threads) per bucket: per-node LDS count + scan, LDS scatter,
// coalesced linear write to packed; emits offs.
// ---------------------------------------------------------------------------
__global__ __launch_bounds__(512) void bucket_to_csr(
    const int2* __restrict__ bucketed, const int* __restrict__ bbase,
    int2* __restrict__ packed, int* __restrict__ offs)
{
    __shared__ int cnt[256];
    __shared__ int sc[256];
    __shared__ int lcur[256];
    __shared__ int2 buf[BUF_CAP];

    const int b    = blockIdx.x;
    const int t    = threadIdx.x;
    const int base = bbase[b];
    const int nE   = bbase[b + 1] - base;

    if (t < 256) cnt[t] = 0;
    __syncthreads();
    for (int i = t; i < nE; i += 512)
        atomicAdd(&cnt[(bucketed[base + i].x >> 16) & 0xFF], 1);
    __syncthreads();
    if (t < 256) sc[t] = cnt[t];
    __syncthreads();
    #pragma unroll
    for (int off = 1; off < 256; off <<= 1) {
        int u = 0;
        if (t < 256 && t >= off) u = sc[t - off];
        __syncthreads();
        if (t < 256 && t >= off) sc[t] += u;
        __syncthreads();
    }
    if (t < 256) lcur[t] = sc[t] - cnt[t];
    __syncthreads();

    if (nE <= BUF_CAP) {
        for (int i = t; i < nE; i += 512) {
            const int2 e = bucketed[base + i];
            const int  n = (e.x >> 16) & 0xFF;
            const int  p = atomicAdd(&lcur[n], 1);
            buf[p] = make_int2(e.x & 0xFFFF, e.y);
        }
        __syncthreads();
        for (int i = t; i < nE; i += 512)
            packed[base + i] = buf[i];
    } else {
        for (int i = t; i < nE; i += 512) {
            const int2 e = bucketed[base + i];
            const int  n = (e.x >> 16) & 0xFF;
            const int  p = atomicAdd(&lcur[n], 1);
            packed[base + p] = make_int2(e.x & 0xFFFF, e.y);
        }
    }

    if (t < 256) {
        const int node = b * 256 + t;
        if (node < N_NODES) offs[node] = base + (sc[t] - cnt[t]);
    }
    if (b == N_BKT - 1 && t == 0) offs[N_NODES] = N_EDGES;
}

// ---------------------------------------------------------------------------
// Fused SpMM gather + GEMM2 + row L2-normalize.
// 4 waves/block, wave = one 16-row strip:
//   1. gather 16 nodes (lane owns dims 2l,2l+1; fp32 reg accumulate, relu)
//   2. stage bf16 rows in per-wave LDS slab (row stride 136 = 16B-aligned, padded)
//   3. MFMA: A-frags from slab, B-frags (pw2) from L2; bias; normalize; store.
// agg never touches global memory.
// ---------------------------------------------------------------------------
__global__ __launch_bounds__(256) void gather_gemm2(
    const unsigned int* __restrict__ sup, const int2* __restrict__ packed,
    const int* __restrict__ offs, const short8* __restrict__ Bp,
    const float* __restrict__ bias, float* __restrict__ out)
{
    __shared__ __align__(16) unsigned short slab[4][16][136];

    const int wave = threadIdx.x >> 6;
    const int lane = threadIdx.x & 63;
    int strip = blockIdx.x * 4 + wave;
    if (strip >= N_STRIPS) strip = N_STRIPS - 1;   // tail waves duplicate (benign)

    // ---- gather phase ----
    for (int i = 0; i < 16; ++i) {
        const int node = strip * 16 + i;
        const int beg = offs[node];
        const int end = offs[node + 1];
        float ax = 0.f, ay = 0.f;
        int j = beg;
        for (; j + 3 < end; j += 4) {
            const int2 e0 = packed[j];
            const int2 e1 = packed[j + 1];
            const int2 e2 = packed[j + 2];
            const int2 e3 = packed[j + 3];
            const unsigned int u0 = sup[(size_t)e0.x * 64 + lane];
            const unsigned int u1 = sup[(size_t)e1.x * 64 + lane];
            const unsigned int u2 = sup[(size_t)e2.x * 64 + lane];
            const unsigned int u3 = sup[(size_t)e3.x * 64 + lane];
            const float v0 = __int_as_float(e0.y);
            const float v1 = __int_as_float(e1.y);
            const float v2 = __int_as_float(e2.y);
            const float v3 = __int_as_float(e3.y);
            ax += __uint_as_float(u0 << 16) * v0;  ay += __uint_as_float(u0 & 0xffff0000u) * v0;
            ax += __uint_as_float(u1 << 16) * v1;  ay += __uint_as_float(u1 & 0xffff0000u) * v1;
            ax += __uint_as_float(u2 << 16) * v2;  ay += __uint_as_float(u2 & 0xffff0000u) * v2;
            ax += __uint_as_float(u3 << 16) * v3;  ay += __uint_as_float(u3 & 0xffff0000u) * v3;
        }
        for (; j < end; ++j) {
            const int2 e0 = packed[j];
            const unsigned int u0 = sup[(size_t)e0.x * 64 + lane];
            const float v0 = __int_as_float(e0.y);
            ax += __uint_as_float(u0 << 16) * v0;
            ay += __uint_as_float(u0 & 0xffff0000u) * v0;
        }
        ax = fmaxf(ax, 0.f);
        ay = fmaxf(ay, 0.f);
        // bf16 pair -> one 4B LDS store (2-way bank alias: free)
        *reinterpret_cast<unsigned int*>(&slab[wave][i][2 * lane]) =
            (unsigned int)f2bf(ax) | ((unsigned int)f2bf(ay) << 16);
    }
    __syncthreads();   // uniform (no early return); orders slab write -> read

    // ---- MFMA phase ----
    const int m = lane & 15;
    const int q = lane >> 4;

    short8 a[4];
    #pragma unroll
    for (int ks = 0; ks < 4; ++ks)
        a[ks] = *reinterpret_cast<const short8*>(&slab[wave][m][ks * 32 + q * 8]);

    floatx4 acc[8];
    #pragma unroll
    for (int nt = 0; nt < 8; ++nt) { acc[nt][0]=0.f; acc[nt][1]=0.f; acc[nt][2]=0.f; acc[nt][3]=0.f; }

    #pragma unroll
    for (int ks = 0; ks < 4; ++ks) {
        #pragma unroll
        for (int nt = 0; nt < 8; ++nt) {
            const short8 bf = Bp[(ks * 8 + nt) * 64 + lane];
            acc[nt] = __builtin_amdgcn_mfma_f32_16x16x32_bf16(a[ks], bf, acc[nt], 0, 0, 0);
        }
    }

    #pragma unroll
    for (int nt = 0; nt < 8; ++nt) {
        const float bb = bias[nt * 16 + m];
        #pragma unroll
        for (int i = 0; i < 4; ++i) acc[nt][i] += bb;
    }

    float sq[4] = {0.f, 0.f, 0.f, 0.f};
    #pragma unroll
    for (int nt = 0; nt < 8; ++nt)
        #pragma unroll
        for (int i = 0; i < 4; ++i) sq[i] += acc[nt][i] * acc[nt][i];
    #pragma unroll
    for (int i = 0; i < 4; ++i) {
        #pragma unroll
        for (int mask = 1; mask < 16; mask <<= 1)
            sq[i] += __shfl_xor(sq[i], mask);
        sq[i] = 1.0f / sqrtf(sq[i]);
    }

    #pragma unroll
    for (int nt = 0; nt < 8; ++nt) {
        #pragma unroll
        for (int i = 0; i < 4; ++i) {
            const int r = strip * 16 + q * 4 + i;
            out[(size_t)r * DIM + nt * 16 + m] = acc[nt][i] * sq[i];
        }
    }
}

// ---------------------------------------------------------------------------
extern "C" void kernel_launch(void* const* d_in, const int* in_sizes, int n_in,
                              void* d_out, int out_size, void* d_ws, size_t ws_size,
                              hipStream_t stream) {
    const float* x    = (const float*)d_in[0];
    const float* vals = (const float*)d_in[1];
    const float* W_gc = (const float*)d_in[2];
    const float* b_gc = (const float*)d_in[3];
    const float* W2   = (const float*)d_in[4];
    const float* b2   = (const float*)d_in[5];
    const int*   src  = (const int*)d_in[6];
    const int*   dst  = (const int*)d_in[7];

    float* out = (float*)d_out;

    // ws layout (all 16B-aligned). support lives in ws now (gather_gemm2
    // reads it while writing d_out).
    const size_t SUP_B  = (size_t)N_NODES * DIM * 2;      // 12,800,000 (bf16)
    const size_t OFFS_B = 200064;                         // offs[N+1]
    const size_t BH_B   = (size_t)EDGE_BLOCKS * 256 * 4;  // blk_hist 200,704
    const size_t BB_B   = (size_t)EDGE_BLOCKS * 256 * 4;  // blk_base 200,704
    const size_t BKT_B  = 1024;                           // bbase[197]
    const size_t BUK_B  = (size_t)N_EDGES * 8;            // bucketed 6.4 MB
    const size_t PACK_B = (size_t)N_EDGES * 8;            // packed 6.4 MB
    const size_t PW_B   = 32768;

    char* wsb = (char*)d_ws;
    unsigned short* support = (unsigned short*)wsb;
    int*   offs     = (int*)(wsb + SUP_B);
    int*   blk_hist = (int*)(wsb + SUP_B + OFFS_B);
    int*   blk_base = (int*)(wsb + SUP_B + OFFS_B + BH_B);
    int*   bbase    = (int*)(wsb + SUP_B + OFFS_B + BH_B + BB_B);
    int2*  bucketed = (int2*)(wsb + SUP_B + OFFS_B + BH_B + BB_B + BKT_B);
    int2*  packed   = (int2*)(wsb + SUP_B + OFFS_B + BH_B + BB_B + BKT_B + BUK_B);
    uint4* pw1      = (uint4*)(wsb + SUP_B + OFFS_B + BH_B + BB_B + BKT_B + BUK_B + PACK_B);
    uint4* pw2      = (uint4*)(wsb + SUP_B + OFFS_B + BH_B + BB_B + BKT_B + BUK_B + PACK_B + PW_B);

    // 1. pack W -> pw1 (gemm1's B; must precede fused_front)
    pack_w1<<<8, 256, 0, stream>>>(W_gc, pw1);

    // 2. fused: gemm1 || blockwise hist || pack W2 -> pw2
    fused_front<<<FRONT_BLOCKS, 256, 0, stream>>>(
        x, W2, b_gc, dst, pw1, support, blk_hist, pw2);

    // 3. scan histograms -> per-chunk bases + bucket starts
    scan_hist<<<1, 1024, 0, stream>>>(blk_hist, blk_base, bbase);

    // 4. deterministic bucket scatter
    bucket_scatter<<<EDGE_BLOCKS, 256, 0, stream>>>(src, dst, vals, blk_base, bucketed);

    // 5. bucket -> CSR (packed, offs)
    bucket_to_csr<<<N_BKT, 512, 0, stream>>>(bucketed, bbase, packed, offs);

    // 6. fused gather + gemm2 + normalize -> out
    gather_gemm2<<<GEMM_BLOCKS, 256, 0, stream>>>(
        (const unsigned int*)support, packed, offs,
        (const short8*)pw2, b2, out);
}

// Round 8
// 162.178 us; speedup vs baseline: 1.2045x; 1.2045x over previous
//
#include <hip/hip_runtime.h>
#include <hip/hip_bf16.h>

#define N_NODES 50000
#define N_EDGES 800000
#define DIM     128
#define N_STRIPS (N_NODES / 16)               // 3125 exact: 16-row strips
#define N_BKT    ((N_NODES + 255) / 256)      // 196 buckets (dst >> 8)
#define EDGE_BLOCKS ((N_EDGES + 4095) / 4096) // 196 chunks of 4096 edges
#define BUF_CAP  6144                          // LDS edge buffer (mean 4096, 32 sigma)
#define GEMM_BLOCKS ((N_STRIPS + 3) / 4)      // 782
#define HIST_BLOCK0 GEMM_BLOCKS               // 782..978: hist chunks
#define PACK_BLOCK0 (GEMM_BLOCKS + EDGE_BLOCKS) // 978..986: W2 pack
#define FRONT_BLOCKS (PACK_BLOCK0 + 8)        // 986
#define CHUNKS_PER_PART (EDGE_BLOCKS / 4)     // 49 exact

typedef short short8 __attribute__((ext_vector_type(8)));
typedef float floatx4 __attribute__((ext_vector_type(4)));

// fp32 -> bf16 (RNE) bit pattern
__device__ inline unsigned short f2bf(float f) {
    __hip_bfloat16 h = __float2bfloat16(f);
    return *reinterpret_cast<unsigned short*>(&h);
}

// ---------------------------------------------------------------------------
// Prologue: pack W into MFMA B-fragment order (p1), 8 blocks.
// slot s=(ks*8+nt)*64+lane holds 8 bf16: B[ks*32+(lane>>4)*8+j][nt*16+(lane&15)]
// ---------------------------------------------------------------------------
__global__ __launch_bounds__(256) void pack_w1(
    const float* __restrict__ W, uint4* __restrict__ p1)
{
    const int s    = blockIdx.x * 256 + threadIdx.x;     // 0..2047
    const int lane = s & 63;
    const int nt   = (s >> 6) & 7;
    const int ks   = s >> 9;
    const int m    = lane & 15;
    const int q    = lane >> 4;
    unsigned short e[8];
    #pragma unroll
    for (int j = 0; j < 8; ++j)
        e[j] = f2bf(W[(ks * 32 + q * 8 + j) * DIM + nt * 16 + m]);
    uint4 o;
    o.x = (unsigned)e[0] | ((unsigned)e[1] << 16);
    o.y = (unsigned)e[2] | ((unsigned)e[3] << 16);
    o.z = (unsigned)e[4] | ((unsigned)e[5] << 16);
    o.w = (unsigned)e[6] | ((unsigned)e[7] << 16);
    p1[s] = o;
}

// ---------------------------------------------------------------------------
// Fused front end. Block ranges:
//  [0, 782):   GEMM1 (MFMA, no LDS): support = bf16(x @ W + b), 4 waves/block
//  [782, 978): per-chunk bucket histogram (bucket = dst>>8) -> blk_hist
//  [978, 986): pack W2 (B[k][n]=W2[n][k]) -> p2 (consumed 4 dispatches later)
// All data-independent -> co-scheduled in one dispatch.
// ---------------------------------------------------------------------------
__global__ __launch_bounds__(256) void fused_front(
    const float* __restrict__ x, const float* __restrict__ W2,
    const float* __restrict__ bias, const int* __restrict__ dst,
    const uint4* __restrict__ p1,
    unsigned short* __restrict__ support, int* __restrict__ blk_hist,
    uint4* __restrict__ p2)
{
    __shared__ int bh[256];
    const int t = threadIdx.x;

    if (blockIdx.x < HIST_BLOCK0) {
        // ---------------- GEMM1 ----------------
        const int wave  = t >> 6;
        const int lane  = t & 63;
        const int strip = blockIdx.x * 4 + wave;
        if (strip >= N_STRIPS) return;
        const int m = lane & 15;
        const int q = lane >> 4;
        const int row = strip * 16 + m;

        short8 a[4];
        const float4* xr = reinterpret_cast<const float4*>(&x[(size_t)row * DIM]);
        #pragma unroll
        for (int ks = 0; ks < 4; ++ks) {
            const float4 f0 = xr[ks * 8 + q * 2];
            const float4 f1 = xr[ks * 8 + q * 2 + 1];
            short8 tt;
            tt[0] = (short)f2bf(f0.x); tt[1] = (short)f2bf(f0.y);
            tt[2] = (short)f2bf(f0.z); tt[3] = (short)f2bf(f0.w);
            tt[4] = (short)f2bf(f1.x); tt[5] = (short)f2bf(f1.y);
            tt[6] = (short)f2bf(f1.z); tt[7] = (short)f2bf(f1.w);
            a[ks] = tt;
        }

        floatx4 acc[8];
        #pragma unroll
        for (int nt = 0; nt < 8; ++nt) { acc[nt][0]=0.f; acc[nt][1]=0.f; acc[nt][2]=0.f; acc[nt][3]=0.f; }

        const short8* Bp = (const short8*)p1;
        #pragma unroll
        for (int ks = 0; ks < 4; ++ks) {
            #pragma unroll
            for (int nt = 0; nt < 8; ++nt) {
                const short8 bf = Bp[(ks * 8 + nt) * 64 + lane];
                acc[nt] = __builtin_amdgcn_mfma_f32_16x16x32_bf16(a[ks], bf, acc[nt], 0, 0, 0);
            }
        }

        #pragma unroll
        for (int nt = 0; nt < 8; ++nt) {
            const float bb = bias[nt * 16 + m];
            #pragma unroll
            for (int i = 0; i < 4; ++i) {
                const int r = strip * 16 + q * 4 + i;
                support[(size_t)r * DIM + nt * 16 + m] = f2bf(acc[nt][i] + bb);
            }
        }
    } else if (blockIdx.x < PACK_BLOCK0) {
        // ---------------- blockwise bucket histogram ----------------
        const int chunk = blockIdx.x - HIST_BLOCK0;
        bh[t] = 0;
        __syncthreads();
        const int base   = chunk * 4096;
        const int navail = min(4096, N_EDGES - base);    // 4096 or 1280; %4==0
        const int4* d4 = reinterpret_cast<const int4*>(dst + base);
        #pragma unroll
        for (int i = 0; i < 4; ++i) {
            const int j = t + i * 256;
            if (j * 4 < navail) {
                const int4 d = d4[j];
                atomicAdd(&bh[d.x >> 8], 1);
                atomicAdd(&bh[d.y >> 8], 1);
                atomicAdd(&bh[d.z >> 8], 1);
                atomicAdd(&bh[d.w >> 8], 1);
            }
        }
        __syncthreads();
        blk_hist[chunk * 256 + t] = bh[t];
    } else {
        // ---------------- pack W2 ----------------
        const int pb   = blockIdx.x - PACK_BLOCK0;       // 0..7
        const int s    = pb * 256 + t;                   // 0..2047
        const int lane = s & 63;
        const int nt   = (s >> 6) & 7;
        const int ks   = s >> 9;
        const int m    = lane & 15;
        const int q    = lane >> 4;
        const float4 f0 = *reinterpret_cast<const float4*>(&W2[(nt * 16 + m) * DIM + ks * 32 + q * 8]);
        const float4 f1 = *reinterpret_cast<const float4*>(&W2[(nt * 16 + m) * DIM + ks * 32 + q * 8 + 4]);
        unsigned short e[8];
        e[0] = f2bf(f0.x); e[1] = f2bf(f0.y); e[2] = f2bf(f0.z); e[3] = f2bf(f0.w);
        e[4] = f2bf(f1.x); e[5] = f2bf(f1.y); e[6] = f2bf(f1.z); e[7] = f2bf(f1.w);
        uint4 o;
        o.x = (unsigned)e[0] | ((unsigned)e[1] << 16);
        o.y = (unsigned)e[2] | ((unsigned)e[3] << 16);
        o.z = (unsigned)e[4] | ((unsigned)e[5] << 16);
        o.w = (unsigned)e[6] | ((unsigned)e[7] << 16);
        p2[s] = o;
    }
}

// ---------------------------------------------------------------------------
// Scan per-chunk histograms -> per-chunk per-bucket scatter bases (blk_base)
// + bucket starts (bbase[197]). One block x 1024: 4 parts x 256 buckets.
// Per-chunk prefixes held in registers -> single global pass each way.
// ---------------------------------------------------------------------------
__global__ __launch_bounds__(1024) void scan_hist(
    const int* __restrict__ blk_hist, int* __restrict__ blk_base,
    int* __restrict__ bbase)
{
    __shared__ int psum[4][256];
    __shared__ int stot[256];
    __shared__ int sinc[256];

    const int t    = threadIdx.x;
    const int b    = t & 255;
    const int part = t >> 8;
    const int c0   = part * CHUNKS_PER_PART;

    int pre[CHUNKS_PER_PART];
    int run = 0;
    #pragma unroll
    for (int k = 0; k < CHUNKS_PER_PART; ++k) {
        const int v = blk_hist[(c0 + k) * 256 + b];
        pre[k] = run;
        run += v;
    }
    psum[part][b] = run;
    __syncthreads();

    if (part == 0) {
        const int tot = psum[0][b] + psum[1][b] + psum[2][b] + psum[3][b];
        stot[b] = tot;
        sinc[b] = tot;
    }
    __syncthreads();
    for (int off = 1; off < 256; off <<= 1) {
        int u = 0;
        if (part == 0 && b >= off) u = sinc[b - off];
        __syncthreads();
        if (part == 0 && b >= off) sinc[b] += u;
        __syncthreads();
    }
    const int ex = sinc[b] - stot[b];        // exclusive bucket base
    if (part == 0 && b < N_BKT) bbase[b] = ex;
    if (t == 0) bbase[N_BKT] = N_EDGES;

    int partbase = 0;
    #pragma unroll
    for (int p = 0; p < 4; ++p) if (p < part) partbase += psum[p][b];
    const int add = ex + partbase;
    #pragma unroll
    for (int k = 0; k < CHUNKS_PER_PART; ++k)
        blk_base[(c0 + k) * 256 + b] = pre[k] + add;
}

// ---------------------------------------------------------------------------
// Deterministic bucket scatter: bases precomputed per (chunk,bucket); only
// LDS atomics for within-chunk ordering. Writes land in contiguous runs.
// Payload: word0 = src | (dst&0xFF)<<16, word1 = val bits.
// ---------------------------------------------------------------------------
__global__ __launch_bounds__(256) void bucket_scatter(
    const int* __restrict__ src, const int* __restrict__ dst,
    const float* __restrict__ vals, const int* __restrict__ blk_base,
    int2* __restrict__ bucketed)
{
    __shared__ int rcur[256];
    const int t     = threadIdx.x;
    const int chunk = blockIdx.x;
    rcur[t] = blk_base[chunk * 256 + t];
    __syncthreads();

    const int base   = chunk * 4096;
    const int navail = min(4096, N_EDGES - base);
    const int4*   s4 = reinterpret_cast<const int4*>(src + base);
    const int4*   d4 = reinterpret_cast<const int4*>(dst + base);
    const float4* v4 = reinterpret_cast<const float4*>(vals + base);
    #pragma unroll
    for (int i = 0; i < 4; ++i) {
        const int j = t + i * 256;
        if (j * 4 < navail) {
            const int4   s = s4[j];
            const int4   d = d4[j];
            const float4 v = v4[j];
            int p;
            p = atomicAdd(&rcur[d.x >> 8], 1);
            bucketed[p] = make_int2((s.x & 0xFFFF) | ((d.x & 0xFF) << 16), __float_as_int(v.x));
            p = atomicAdd(&rcur[d.y >> 8], 1);
            bucketed[p] = make_int2((s.y & 0xFFFF) | ((d.y & 0xFF) << 16), __float_as_int(v.y));
            p = atomicAdd(&rcur[d.z >> 8], 1);
            bucketed[p] = make_int2((s.z & 0xFFFF) | ((d.z & 0xFF) << 16), __float_as_int(v.z));
            p = atomicAdd(&rcur[d.w >> 8], 1);
            bucketed[p] = make_int2((s.w & 0xFFFF) | ((d.w & 0xFF) << 16), __float_as_int(v.w));
        }
    }
}

// ---------------------------------------------------------------------------
// One block (512 threads) per bucket: per-node LDS count + scan, LDS scatter,
// coalesced linear write to packed; emits offs.
// ---------------------------------------------------------------------------
__global__ __launch_bounds__(512) void bucket_to_csr(
    const int2* __restrict__ bucketed, const int* __restrict__ bbase,
    int2* __restrict__ packed, int* __restrict__ offs)
{
    __shared__ int cnt[256];
    __shared__ int sc[256];
    __shared__ int lcur[256];
    __shared__ int2 buf[BUF_CAP];

    const int b    = blockIdx.x;
    const int t    = threadIdx.x;
    const int base = bbase[b];
    const int nE   = bbase[b + 1] - base;

    if (t < 256) cnt[t] = 0;
    __syncthreads();
    for (int i = t; i < nE; i += 512)
        atomicAdd(&cnt[(bucketed[base + i].x >> 16) & 0xFF], 1);
    __syncthreads();
    if (t < 256) sc[t] = cnt[t];
    __syncthreads();
    #pragma unroll
    for (int off = 1; off < 256; off <<= 1) {
        int u = 0;
        if (t < 256 && t >= off) u = sc[t - off];
        __syncthreads();
        if (t < 256 && t >= off) sc[t] += u;
        __syncthreads();
    }
    if (t < 256) lcur[t] = sc[t] - cnt[t];
    __syncthreads();

    if (nE <= BUF_CAP) {
        for (int i = t; i < nE; i += 512) {
            const int2 e = bucketed[base + i];
            const int  n = (e.x >> 16) & 0xFF;
            const int  p = atomicAdd(&lcur[n], 1);
            buf[p] = make_int2(e.x & 0xFFFF, e.y);
        }
        __syncthreads();
        for (int i = t; i < nE; i += 512)
            packed[base + i] = buf[i];
    } else {
        for (int i = t; i < nE; i += 512) {
            const int2 e = bucketed[base + i];
            const int  n = (e.x >> 16) & 0xFF;
            const int  p = atomicAdd(&lcur[n], 1);
            packed[base + p] = make_int2(e.x & 0xFFFF, e.y);
        }
    }

    if (t < 256) {
        const int node = b * 256 + t;
        if (node < N_NODES) offs[node] = base + (sc[t] - cnt[t]);
    }
    if (b == N_BKT - 1 && t == 0) offs[N_NODES] = N_EDGES;
}

// ---------------------------------------------------------------------------
// SpMM gather (bf16 support): ONE WAVE PER NODE (50K waves -> max MLP),
// lane owns 2 dims. Edge loop unrolled x8: 8 independent row loads in
// flight per lane. relu folded in; agg stored bf16 for GEMM2 A-fragments.
// ---------------------------------------------------------------------------
__global__ __launch_bounds__(256) void csr_gather_bf16(
    const unsigned int* __restrict__ sup, const int2* __restrict__ packed,
    const int* __restrict__ offs, unsigned int* __restrict__ agg)
{
    const int node = (blockIdx.x * 256 + threadIdx.x) >> 6;
    const int lane = threadIdx.x & 63;
    if (node >= N_NODES) return;
    const int beg = offs[node];
    const int end = offs[node + 1];

    float ax = 0.f, ay = 0.f;
    int j = beg;
    for (; j + 7 < end; j += 8) {
        int2 e[8];
        unsigned int u[8];
        #pragma unroll
        for (int k = 0; k < 8; ++k) e[k] = packed[j + k];
        #pragma unroll
        for (int k = 0; k < 8; ++k) u[k] = sup[(size_t)e[k].x * 64 + lane];
        #pragma unroll
        for (int k = 0; k < 8; ++k) {
            const float v = __int_as_float(e[k].y);
            ax += __uint_as_float(u[k] << 16) * v;
            ay += __uint_as_float(u[k] & 0xffff0000u) * v;
        }
    }
    for (; j + 3 < end; j += 4) {
        int2 e[4];
        unsigned int u[4];
        #pragma unroll
        for (int k = 0; k < 4; ++k) e[k] = packed[j + k];
        #pragma unroll
        for (int k = 0; k < 4; ++k) u[k] = sup[(size_t)e[k].x * 64 + lane];
        #pragma unroll
        for (int k = 0; k < 4; ++k) {
            const float v = __int_as_float(e[k].y);
            ax += __uint_as_float(u[k] << 16) * v;
            ay += __uint_as_float(u[k] & 0xffff0000u) * v;
        }
    }
    for (; j < end; ++j) {
        const int2 e0 = packed[j];
        const unsigned int u0 = sup[(size_t)e0.x * 64 + lane];
        const float v0 = __int_as_float(e0.y);
        ax += __uint_as_float(u0 << 16) * v0;
        ay += __uint_as_float(u0 & 0xffff0000u) * v0;
    }
    ax = fmaxf(ax, 0.f);
    ay = fmaxf(ay, 0.f);
    agg[(size_t)node * 64 + lane] = (unsigned int)f2bf(ax) | ((unsigned int)f2bf(ay) << 16);
}

// ---------------------------------------------------------------------------
// GEMM2 (MFMA, no LDS) + row L2-normalize: out = rownorm(agg @ W2^T + b2)
// ---------------------------------------------------------------------------
__global__ __launch_bounds__(256) void gemm2_mfma(
    const short8* __restrict__ aggv, const short8* __restrict__ Bp,
    const float* __restrict__ bias, float* __restrict__ out)
{
    const int wave  = threadIdx.x >> 6;
    const int lane  = threadIdx.x & 63;
    const int strip = blockIdx.x * 4 + wave;
    if (strip >= N_STRIPS) return;
    const int m = lane & 15;
    const int q = lane >> 4;
    const int row = strip * 16 + m;

    short8 a[4];
    #pragma unroll
    for (int ks = 0; ks < 4; ++ks)
        a[ks] = aggv[(size_t)row * (DIM / 8) + ks * 4 + q];

    floatx4 acc[8];
    #pragma unroll
    for (int nt = 0; nt < 8; ++nt) { acc[nt][0]=0.f; acc[nt][1]=0.f; acc[nt][2]=0.f; acc[nt][3]=0.f; }

    #pragma unroll
    for (int ks = 0; ks < 4; ++ks) {
        #pragma unroll
        for (int nt = 0; nt < 8; ++nt) {
            const short8 bf = Bp[(ks * 8 + nt) * 64 + lane];
            acc[nt] = __builtin_amdgcn_mfma_f32_16x16x32_bf16(a[ks], bf, acc[nt], 0, 0, 0);
        }
    }

    #pragma unroll
    for (int nt = 0; nt < 8; ++nt) {
        const float bb = bias[nt * 16 + m];
        #pragma unroll
        for (int i = 0; i < 4; ++i) acc[nt][i] += bb;
    }

    float sq[4] = {0.f, 0.f, 0.f, 0.f};
    #pragma unroll
    for (int nt = 0; nt < 8; ++nt)
        #pragma unroll
        for (int i = 0; i < 4; ++i) sq[i] += acc[nt][i] * acc[nt][i];
    #pragma unroll
    for (int i = 0; i < 4; ++i) {
        #pragma unroll
        for (int mask = 1; mask < 16; mask <<= 1)
            sq[i] += __shfl_xor(sq[i], mask);
        sq[i] = 1.0f / sqrtf(sq[i]);
    }

    #pragma unroll
    for (int nt = 0; nt < 8; ++nt) {
        #pragma unroll
        for (int i = 0; i < 4; ++i) {
            const int r = strip * 16 + q * 4 + i;
            out[(size_t)r * DIM + nt * 16 + m] = acc[nt][i] * sq[i];
        }
    }
}

// ---------------------------------------------------------------------------
extern "C" void kernel_launch(void* const* d_in, const int* in_sizes, int n_in,
                              void* d_out, int out_size, void* d_ws, size_t ws_size,
                              hipStream_t stream) {
    const float* x    = (const float*)d_in[0];
    const float* vals = (const float*)d_in[1];
    const float* W_gc = (const float*)d_in[2];
    const float* b_gc = (const float*)d_in[3];
    const float* W2   = (const float*)d_in[4];
    const float* b2   = (const float*)d_in[5];
    const int*   src  = (const int*)d_in[6];
    const int*   dst  = (const int*)d_in[7];

    unsigned short* support = (unsigned short*)d_out;   // bf16 staging in d_out
    float* out = (float*)d_out;

    // ws layout (all 16B-aligned)
    const size_t AGG_B  = (size_t)N_NODES * DIM * 2;      // 12,800,000 (bf16)
    const size_t OFFS_B = 200064;                         // offs[N+1]
    const size_t BH_B   = (size_t)EDGE_BLOCKS * 256 * 4;  // blk_hist 200,704
    const size_t BB_B   = (size_t)EDGE_BLOCKS * 256 * 4;  // blk_base 200,704
    const size_t BKT_B  = 1024;                           // bbase[197]
    const size_t BUK_B  = (size_t)N_EDGES * 8;            // bucketed 6.4 MB
    const size_t PACK_B = (size_t)N_EDGES * 8;            // packed 6.4 MB
    const size_t PW_B   = 32768;

    char* wsb = (char*)d_ws;
    unsigned int* agg = (unsigned int*)wsb;
    int*   offs     = (int*)(wsb + AGG_B);
    int*   blk_hist = (int*)(wsb + AGG_B + OFFS_B);
    int*   blk_base = (int*)(wsb + AGG_B + OFFS_B + BH_B);
    int*   bbase    = (int*)(wsb + AGG_B + OFFS_B + BH_B + BB_B);
    int2*  bucketed = (int2*)(wsb + AGG_B + OFFS_B + BH_B + BB_B + BKT_B);
    int2*  packed   = (int2*)(wsb + AGG_B + OFFS_B + BH_B + BB_B + BKT_B + BUK_B);
    uint4* pw1      = (uint4*)(wsb + AGG_B + OFFS_B + BH_B + BB_B + BKT_B + BUK_B + PACK_B);
    uint4* pw2      = (uint4*)(wsb + AGG_B + OFFS_B + BH_B + BB_B + BKT_B + BUK_B + PACK_B + PW_B);

    // 1. pack W -> pw1 (gemm1's B; must precede fused_front)
    pack_w1<<<8, 256, 0, stream>>>(W_gc, pw1);

    // 2. fused: gemm1 || blockwise hist || pack W2 -> pw2
    fused_front<<<FRONT_BLOCKS, 256, 0, stream>>>(
        x, W2, b_gc, dst, pw1, support, blk_hist, pw2);

    // 3. scan histograms -> per-chunk bases + bucket starts
    scan_hist<<<1, 1024, 0, stream>>>(blk_hist, blk_base, bbase);

    // 4. deterministic bucket scatter
    bucket_scatter<<<EDGE_BLOCKS, 256, 0, stream>>>(src, dst, vals, blk_base, bucketed);

    // 5. bucket -> CSR (packed, offs)
    bucket_to_csr<<<N_BKT, 512, 0, stream>>>(bucketed, bbase, packed, offs);

    // 6. agg = bf16(relu(segment_sum(support[src]*val, dst)))  [one wave/node]
    csr_gather_bf16<<<(N_NODES * 64 + 255) / 256, 256, 0, stream>>>(
        (const unsigned int*)support, packed, offs, agg);

    // 7. out = rownorm(agg @ W2^T + b2)
    gemm2_mfma<<<GEMM_BLOCKS, 256, 0, stream>>>(
        (const short8*)agg, (const short8*)pw2, b2, out);
}